// Round 1
// baseline (2061.548 us; speedup 1.0000x reference)
//
#include <hip/hip_runtime.h>
#include <stdint.h>

#define N_VAR 2097152
#define M_CHK 1048576
#define DVv 3
#define DCc 6
#define T_IT 10
#define E_EDGE (N_VAR * DVv)   // 6291456
#define KQ 8

// ---------- init: v2c0[e] = llr[e/3], one thread per variable ----------
__global__ void init_v2c_kernel(const float* __restrict__ llr, float* __restrict__ v2c) {
    int v = blockIdx.x * blockDim.x + threadIdx.x;
    if (v >= N_VAR) return;
    float x = llr[v];
    int e0 = v * DVv;
    v2c[e0 + 0] = x;
    v2c[e0 + 1] = x;
    v2c[e0 + 2] = x;
}

// ---------- CSR build: chk_edges[c*6 + slot] = e (slot order arbitrary) ----------
__global__ void build_csr_kernel(const int* __restrict__ chk_idx,
                                 int* __restrict__ cnt,
                                 int* __restrict__ chk_edges) {
    int e = blockIdx.x * blockDim.x + threadIdx.x;
    if (e >= E_EDGE) return;
    int c = chk_idx[e];
    int s = atomicAdd(&cnt[c], 1);
    chk_edges[c * DCc + s] = e;
}

// ---------- check-node pass: per check compute min1/min2/first/parity,
//            quantize magnitudes with beta folded in, pack to one u32 ----------
__global__ void check_kernel(const float* __restrict__ v2c,
                             const int* __restrict__ chk_edges,
                             const float* __restrict__ beta,
                             const float* __restrict__ thresholds,
                             int t,
                             uint32_t* __restrict__ summary) {
    int c = blockIdx.x * blockDim.x + threadIdx.x;
    if (c >= M_CHK) return;
    float b = beta[t];
    const float* thr = thresholds + t * KQ;
    float th1 = thr[1], th2 = thr[2], th3 = thr[3], th4 = thr[4];
    float th5 = thr[5], th6 = thr[6], th7 = thr[7];

    int base = c * DCc;
    float mags[DCc];
    uint64_t keys[DCc];
    uint32_t par = 0;
    uint64_t minkey = ~0ull;
#pragma unroll
    for (int j = 0; j < DCc; ++j) {
        int e = chk_edges[base + j];
        float x = v2c[e];                       // random gather
        par ^= (x < 0.0f) ? 1u : 0u;
        float mg = fabsf(x);
        uint64_t key = (((uint64_t)__float_as_uint(mg)) << 23) | (uint32_t)e;
        mags[j] = mg;
        keys[j] = key;
        minkey = (key < minkey) ? key : minkey;
    }
    uint32_t first = (uint32_t)(minkey & 0x7FFFFFu);
    float min1 = __uint_as_float((uint32_t)(minkey >> 23));
    float min2 = INFINITY;
#pragma unroll
    for (int j = 0; j < DCc; ++j) {
        if (keys[j] != minkey) min2 = fminf(min2, mags[j]);
    }
    // DC=6 so min2 is always finite (degree-1 guard unnecessary)

    // |raw| = |b * mval| bit-exactly (sign flips in the reference are exact *(+-1))
    float m1 = fabsf(b * min1);
    float m2 = fabsf(b * min2);
    uint32_t q1 = (uint32_t)(m1 >= th1) + (uint32_t)(m1 >= th2) + (uint32_t)(m1 >= th3)
                + (uint32_t)(m1 >= th4) + (uint32_t)(m1 >= th5) + (uint32_t)(m1 >= th6)
                + (uint32_t)(m1 >= th7);
    uint32_t q2 = (uint32_t)(m2 >= th1) + (uint32_t)(m2 >= th2) + (uint32_t)(m2 >= th3)
                + (uint32_t)(m2 >= th4) + (uint32_t)(m2 >= th5) + (uint32_t)(m2 >= th6)
                + (uint32_t)(m2 >= th7);

    summary[c] = first | (par << 23) | (q1 << 24) | (q2 << 27);
}

// ---------- variable-node pass ----------
__global__ void var_kernel(const float* __restrict__ llr,
                           const int* __restrict__ chk_idx,
                           float* __restrict__ v2c,            // in-place (own edges only)
                           const uint32_t* __restrict__ summary,
                           const float* __restrict__ beta,
                           const float* __restrict__ alpha,
                           const float* __restrict__ thresholds,
                           int t, int last,
                           float* __restrict__ out) {
    int v = blockIdx.x * blockDim.x + threadIdx.x;
    if (v >= N_VAR) return;
    float b = beta[t];
    float a = alpha[t];
    uint32_t negb = (b < 0.0f) ? 1u : 0u;
    const float* thr = thresholds + t * KQ;
    float tl[KQ];
#pragma unroll
    for (int k = 0; k < KQ; ++k) tl[k] = thr[k];

    int e0 = v * DVv;
    float c2[DVv];
#pragma unroll
    for (int i = 0; i < DVv; ++i) {
        int e = e0 + i;
        int c = chk_idx[e];
        uint32_t w = summary[c];               // random gather from 4 MB set
        float old = v2c[e];
        uint32_t isfirst = ((uint32_t)e == (w & 0x7FFFFFu)) ? 1u : 0u;
        uint32_t q = (isfirst ? (w >> 27) : (w >> 24)) & 7u;
        float mg = tl[q];
        uint32_t neg = negb ^ ((w >> 23) & 1u) ^ ((old < 0.0f) ? 1u : 0u);
        c2[i] = neg ? -mg : mg;
    }
    float s = (c2[0] + c2[1]) + c2[2];         // reference summation order
    float post = llr[v] + s;
#pragma unroll
    for (int i = 0; i < DVv; ++i) {
        v2c[e0 + i] = a * (post - c2[i]);
    }
    if (last) {
        out[v] = (post < 0.0f) ? 1.0f : 0.0f;  // decoded
        out[N_VAR + v] = post;                 // posterior
        if (v == 0) out[2 * N_VAR] = 10.0f;    // jnp.int32(T) as float
    }
}

extern "C" void kernel_launch(void* const* d_in, const int* in_sizes, int n_in,
                              void* d_out, int out_size, void* d_ws, size_t ws_size,
                              hipStream_t stream) {
    const float* llr        = (const float*)d_in[0];
    const int*   var_idx    = (const int*)d_in[1];   (void)var_idx; // implicit: e/3
    const int*   chk_idx    = (const int*)d_in[2];
    const float* beta       = (const float*)d_in[3];
    const float* alpha      = (const float*)d_in[4];
    const float* thresholds = (const float*)d_in[5];
    float* out = (float*)d_out;

    char* wsb = (char*)d_ws;
    float*    v2c       = (float*)wsb;                                   // E*4
    int*      chk_edges = (int*)(wsb + (size_t)E_EDGE * 4);              // E*4
    uint32_t* summary   = (uint32_t*)(wsb + (size_t)2 * E_EDGE * 4);     // M*4
    int*      cnt       = (int*)(wsb + (size_t)2 * E_EDGE * 4 + (size_t)M_CHK * 4); // M*4

    hipMemsetAsync(cnt, 0, (size_t)M_CHK * 4, stream);

    const int B = 256;
    init_v2c_kernel<<<(N_VAR + B - 1) / B, B, 0, stream>>>(llr, v2c);
    build_csr_kernel<<<(E_EDGE + B - 1) / B, B, 0, stream>>>(chk_idx, cnt, chk_edges);

    for (int t = 0; t < T_IT; ++t) {
        check_kernel<<<(M_CHK + B - 1) / B, B, 0, stream>>>(v2c, chk_edges, beta, thresholds, t, summary);
        var_kernel<<<(N_VAR + B - 1) / B, B, 0, stream>>>(llr, chk_idx, v2c, summary,
                                                          beta, alpha, thresholds, t,
                                                          (t == T_IT - 1) ? 1 : 0, out);
    }
}

// Round 2
// 1543.703 us; speedup vs baseline: 1.3355x; 1.3355x over previous
//
#include <hip/hip_runtime.h>
#include <stdint.h>

#define N_VAR 2097152
#define M_CHK 1048576
#define DVv 3
#define DCc 6
#define T_IT 10
#define E_EDGE (N_VAR * DVv)   // 6291456
#define KQ 8

// bucketed CSR build parameters
#define BUCKETS 512
#define CPB 2048               // checks per bucket   (M_CHK / BUCKETS)
#define EPB (CPB * DCc)        // edges per bucket = 12288 (exact: (3,6)-regular)
#define CHUNK 8192             // edges per bin block
#define BIN_BLOCKS (E_EDGE / CHUNK)  // 768

// ---------- init: v2c0[e] = llr[e/3], one thread per variable ----------
__global__ void init_v2c_kernel(const float* __restrict__ llr, float* __restrict__ v2c) {
    int v = blockIdx.x * blockDim.x + threadIdx.x;
    if (v >= N_VAR) return;
    float x = llr[v];
    int e0 = v * DVv;
    v2c[e0 + 0] = x;
    v2c[e0 + 1] = x;
    v2c[e0 + 2] = x;
}

// ---------- phase 1: bin edges into 512 buckets of 2048 checks ----------
// Each block handles CHUNK contiguous edges: LDS histogram -> one global
// atomic per (block,bucket) to reserve a contiguous segment -> write packed
// (clow,e) u64 into the private segment (spatially local, same-XCD writes).
__global__ __launch_bounds__(256) void bin_kernel(const int* __restrict__ chk_idx,
                                                  uint32_t* __restrict__ gcursor,
                                                  uint64_t* __restrict__ interm) {
    __shared__ uint32_t cnt[BUCKETS];
    __shared__ uint32_t cur[BUCKETS];
    __shared__ uint32_t gbase[BUCKETS];
    const int t = threadIdx.x;
    const int base = blockIdx.x * CHUNK;
    for (int j = t; j < BUCKETS; j += 256) { cnt[j] = 0; cur[j] = 0; }
    __syncthreads();
    int c[CHUNK / 256];
#pragma unroll
    for (int k = 0; k < CHUNK / 256; ++k) {
        c[k] = chk_idx[base + t + 256 * k];
        atomicAdd(&cnt[c[k] >> 11], 1u);
    }
    __syncthreads();
    for (int j = t; j < BUCKETS; j += 256) gbase[j] = atomicAdd(&gcursor[j], cnt[j]);
    __syncthreads();
#pragma unroll
    for (int k = 0; k < CHUNK / 256; ++k) {
        int cc = c[k];
        int b = cc >> 11;
        uint32_t p = atomicAdd(&cur[b], 1u);
        uint32_t e = (uint32_t)(base + t + 256 * k);
        interm[(size_t)b * EPB + gbase[b] + p] =
            (((uint64_t)(uint32_t)(cc & (CPB - 1))) << 32) | e;
    }
}

// ---------- phase 2: place each bucket's edges into chk_edges via LDS ----------
__global__ __launch_bounds__(256) void place_kernel(const uint64_t* __restrict__ interm,
                                                    int* __restrict__ chk_edges) {
    __shared__ int win[EPB];            // 48 KB
    __shared__ uint32_t ccnt[CPB];      // 8 KB
    const int t = threadIdx.x;
    const int b = blockIdx.x;
    for (int j = t; j < CPB; j += 256) ccnt[j] = 0;
    __syncthreads();
    const uint64_t* src = interm + (size_t)b * EPB;
    for (int k = 0; k < EPB / 256; ++k) {
        uint64_t w = src[t + 256 * k];
        uint32_t clow = (uint32_t)(w >> 32);
        uint32_t e = (uint32_t)w;
        uint32_t s = atomicAdd(&ccnt[clow], 1u);
        win[clow * DCc + s] = (int)e;
    }
    __syncthreads();
    int* dst = chk_edges + (size_t)b * EPB;   // == chk_edges + (b*CPB)*6
    for (int j = t; j < EPB; j += 256) dst[j] = win[j];
}

// ---------- check-node pass ----------
__global__ void check_kernel(const float* __restrict__ v2c,
                             const int* __restrict__ chk_edges,
                             const float* __restrict__ beta,
                             const float* __restrict__ thresholds,
                             int t,
                             uint32_t* __restrict__ summary) {
    int c = blockIdx.x * blockDim.x + threadIdx.x;
    if (c >= M_CHK) return;
    float b = beta[t];
    const float* thr = thresholds + t * KQ;
    float th1 = thr[1], th2 = thr[2], th3 = thr[3], th4 = thr[4];
    float th5 = thr[5], th6 = thr[6], th7 = thr[7];

    int base = c * DCc;
    float mags[DCc];
    uint64_t keys[DCc];
    uint32_t par = 0;
    uint64_t minkey = ~0ull;
#pragma unroll
    for (int j = 0; j < DCc; ++j) {
        int e = chk_edges[base + j];
        float x = v2c[e];                       // random gather
        par ^= (x < 0.0f) ? 1u : 0u;
        float mg = fabsf(x);
        uint64_t key = (((uint64_t)__float_as_uint(mg)) << 23) | (uint32_t)e;
        mags[j] = mg;
        keys[j] = key;
        minkey = (key < minkey) ? key : minkey;
    }
    uint32_t first = (uint32_t)(minkey & 0x7FFFFFu);
    float min1 = __uint_as_float((uint32_t)(minkey >> 23));
    float min2 = INFINITY;
#pragma unroll
    for (int j = 0; j < DCc; ++j) {
        if (keys[j] != minkey) min2 = fminf(min2, mags[j]);
    }
    float m1 = fabsf(b * min1);
    float m2 = fabsf(b * min2);
    uint32_t q1 = (uint32_t)(m1 >= th1) + (uint32_t)(m1 >= th2) + (uint32_t)(m1 >= th3)
                + (uint32_t)(m1 >= th4) + (uint32_t)(m1 >= th5) + (uint32_t)(m1 >= th6)
                + (uint32_t)(m1 >= th7);
    uint32_t q2 = (uint32_t)(m2 >= th1) + (uint32_t)(m2 >= th2) + (uint32_t)(m2 >= th3)
                + (uint32_t)(m2 >= th4) + (uint32_t)(m2 >= th5) + (uint32_t)(m2 >= th6)
                + (uint32_t)(m2 >= th7);

    summary[c] = first | (par << 23) | (q1 << 24) | (q2 << 27);
}

// ---------- variable-node pass ----------
__global__ void var_kernel(const float* __restrict__ llr,
                           const int* __restrict__ chk_idx,
                           float* __restrict__ v2c,
                           const uint32_t* __restrict__ summary,
                           const float* __restrict__ beta,
                           const float* __restrict__ alpha,
                           const float* __restrict__ thresholds,
                           int t, int last,
                           float* __restrict__ out) {
    int v = blockIdx.x * blockDim.x + threadIdx.x;
    if (v >= N_VAR) return;
    float b = beta[t];
    float a = alpha[t];
    uint32_t negb = (b < 0.0f) ? 1u : 0u;
    const float* thr = thresholds + t * KQ;
    float tl[KQ];
#pragma unroll
    for (int k = 0; k < KQ; ++k) tl[k] = thr[k];

    int e0 = v * DVv;
    float c2[DVv];
#pragma unroll
    for (int i = 0; i < DVv; ++i) {
        int e = e0 + i;
        int c = chk_idx[e];
        uint32_t w = summary[c];               // random gather from 4 MB set
        float old = v2c[e];
        uint32_t isfirst = ((uint32_t)e == (w & 0x7FFFFFu)) ? 1u : 0u;
        uint32_t q = (isfirst ? (w >> 27) : (w >> 24)) & 7u;
        float mg = tl[q];
        uint32_t neg = negb ^ ((w >> 23) & 1u) ^ ((old < 0.0f) ? 1u : 0u);
        c2[i] = neg ? -mg : mg;
    }
    float s = (c2[0] + c2[1]) + c2[2];         // reference summation order
    float post = llr[v] + s;
#pragma unroll
    for (int i = 0; i < DVv; ++i) {
        v2c[e0 + i] = a * (post - c2[i]);
    }
    if (last) {
        out[v] = (post < 0.0f) ? 1.0f : 0.0f;
        out[N_VAR + v] = post;
        if (v == 0) out[2 * N_VAR] = 10.0f;
    }
}

extern "C" void kernel_launch(void* const* d_in, const int* in_sizes, int n_in,
                              void* d_out, int out_size, void* d_ws, size_t ws_size,
                              hipStream_t stream) {
    const float* llr        = (const float*)d_in[0];
    const int*   var_idx    = (const int*)d_in[1];   (void)var_idx;
    const int*   chk_idx    = (const int*)d_in[2];
    const float* beta       = (const float*)d_in[3];
    const float* alpha      = (const float*)d_in[4];
    const float* thresholds = (const float*)d_in[5];
    float* out = (float*)d_out;

    // workspace layout (interm is dead after place_kernel; alias decode arrays on it):
    //   [0, 50.3MB)      interm (E u64)        | later: v2c (E f32) + summary (M u32)
    //   [50.3, 75.5MB)   chk_edges (E i32)
    //   [75.5MB, +2KB)   gcursor (512 u32)
    char* wsb = (char*)d_ws;
    uint64_t* interm    = (uint64_t*)wsb;
    float*    v2c       = (float*)wsb;                                   // alias interm
    uint32_t* summary   = (uint32_t*)(wsb + (size_t)E_EDGE * 4);         // alias interm hi half
    int*      chk_edges = (int*)(wsb + (size_t)E_EDGE * 8);
    uint32_t* gcursor   = (uint32_t*)(wsb + (size_t)E_EDGE * 8 + (size_t)E_EDGE * 4);

    hipMemsetAsync(gcursor, 0, (size_t)BUCKETS * 4, stream);

    const int B = 256;
    bin_kernel<<<BIN_BLOCKS, B, 0, stream>>>(chk_idx, gcursor, interm);
    place_kernel<<<BUCKETS, B, 0, stream>>>(interm, chk_edges);
    init_v2c_kernel<<<(N_VAR + B - 1) / B, B, 0, stream>>>(llr, v2c);

    for (int t = 0; t < T_IT; ++t) {
        check_kernel<<<(M_CHK + B - 1) / B, B, 0, stream>>>(v2c, chk_edges, beta, thresholds, t, summary);
        var_kernel<<<(N_VAR + B - 1) / B, B, 0, stream>>>(llr, chk_idx, v2c, summary,
                                                          beta, alpha, thresholds, t,
                                                          (t == T_IT - 1) ? 1 : 0, out);
    }
}

// Round 3
// 1272.682 us; speedup vs baseline: 1.6198x; 1.2130x over previous
//
#include <hip/hip_runtime.h>
#include <stdint.h>

#define N_VAR 2097152
#define M_CHK 1048576
#define E_EDGE 6291456
#define T_IT 10

// build params (two halves to cap workspace at the proven ~75.5 MB)
#define CB_HALF 256        // check buckets per half (512 total)
#define CPB 2048           // checks per bucket
#define EPB 12288          // edges per check bucket (exact: (3,6)-regular)
#define VB_HALF 384        // var-edge buckets per half (768 total)
#define EPVB 8192          // edges per var bucket (exact: E = 768*8192)
#define CHUNK 8192
#define NBLK (E_EDGE / CHUNK)   // 768

// ---------- build phase 1a: bin edges by check bucket (one half) ----------
__global__ __launch_bounds__(256) void bin1_kernel(const int* __restrict__ chk_idx,
                                                   uint32_t* __restrict__ gcurA,
                                                   uint64_t* __restrict__ interm,
                                                   int half) {
    __shared__ uint32_t cnt[CB_HALF];
    __shared__ uint32_t cur[CB_HALF];
    const int t = threadIdx.x;
    const int base = blockIdx.x * CHUNK;
    if (t < CB_HALF) cnt[t] = 0;
    __syncthreads();
    int cc[CHUNK / 256];
#pragma unroll
    for (int k = 0; k < CHUNK / 256; ++k) cc[k] = chk_idx[base + t + 256 * k];
#pragma unroll
    for (int k = 0; k < CHUNK / 256; ++k) {
        int cb = cc[k] >> 11;
        if ((cb >> 8) == half) atomicAdd(&cnt[cb & 255], 1u);
    }
    __syncthreads();
    if (t < CB_HALF) cur[t] = atomicAdd(&gcurA[half * CB_HALF + t], cnt[t]);
    __syncthreads();
#pragma unroll
    for (int k = 0; k < CHUNK / 256; ++k) {
        int c = cc[k];
        int cb = c >> 11;
        if ((cb >> 8) == half) {
            int b = cb & 255;
            uint32_t p = atomicAdd(&cur[b], 1u);
            uint32_t e = (uint32_t)(base + t + 256 * k);
            interm[(size_t)b * EPB + p] = (((uint64_t)(uint32_t)(c & (CPB - 1))) << 32) | e;
        }
    }
}

// ---------- build phase 1b: place into chk_edges (edge id per check slot) ----------
__global__ __launch_bounds__(256) void place1_kernel(const uint64_t* __restrict__ interm,
                                                     uint32_t* __restrict__ chk_edges,
                                                     int half) {
    __shared__ uint32_t win[EPB];      // 48 KB
    __shared__ uint32_t ccnt[CPB];     // 8 KB
    const int t = threadIdx.x;
    const int b = blockIdx.x;
    for (int j = t; j < CPB; j += 256) ccnt[j] = 0;
    __syncthreads();
    const uint64_t* src = interm + (size_t)b * EPB;
    for (int k = 0; k < EPB / 256; ++k) {
        uint64_t w = src[t + 256 * k];
        uint32_t clow = (uint32_t)(w >> 32);
        uint32_t s = atomicAdd(&ccnt[clow], 1u);
        win[clow * 6 + s] = (uint32_t)w;
    }
    __syncthreads();
    uint32_t* dst = chk_edges + ((size_t)(half * CB_HALF + b)) * EPB;
    for (int j = t; j < EPB; j += 256) dst[j] = win[j];
}

// ---------- build phase 2a: bin (check-order position -> edge) by edge bucket ----------
__global__ __launch_bounds__(256) void bin2_kernel(const uint32_t* __restrict__ chk_edges,
                                                   uint32_t* __restrict__ gcurB,
                                                   uint64_t* __restrict__ interm,
                                                   int half) {
    __shared__ uint32_t cnt[VB_HALF];
    __shared__ uint32_t cur[VB_HALF];
    const int t = threadIdx.x;
    const int base = blockIdx.x * CHUNK;
    for (int j = t; j < VB_HALF; j += 256) cnt[j] = 0;
    __syncthreads();
    uint32_t ee[CHUNK / 256];
#pragma unroll
    for (int k = 0; k < CHUNK / 256; ++k) ee[k] = chk_edges[base + t + 256 * k];
    const int vb0 = half * VB_HALF;
#pragma unroll
    for (int k = 0; k < CHUNK / 256; ++k) {
        int lb = (int)(ee[k] >> 13) - vb0;
        if (lb >= 0 && lb < VB_HALF) atomicAdd(&cnt[lb], 1u);
    }
    __syncthreads();
    for (int j = t; j < VB_HALF; j += 256) cur[j] = atomicAdd(&gcurB[vb0 + j], cnt[j]);
    __syncthreads();
#pragma unroll
    for (int k = 0; k < CHUNK / 256; ++k) {
        uint32_t e = ee[k];
        int lb = (int)(e >> 13) - vb0;
        if (lb >= 0 && lb < VB_HALF) {
            uint32_t p = atomicAdd(&cur[lb], 1u);
            uint32_t pos = (uint32_t)(base + t + 256 * k);   // position = c*6+s
            uint32_t c = pos / 6u;
            uint32_t s = pos - c * 6u;
            uint32_t destval = (c << 3) | s;                 // 23 bits
            interm[(size_t)lb * EPVB + p] = (((uint64_t)(e & (EPVB - 1))) << 32) | destval;
        }
    }
}

// ---------- build phase 2b: place dest[e] = (c<<3)|s ----------
__global__ __launch_bounds__(256) void place2_kernel(const uint64_t* __restrict__ interm,
                                                     uint32_t* __restrict__ dest,
                                                     int half) {
    __shared__ uint32_t win2[EPVB];    // 32 KB
    const int t = threadIdx.x;
    const int b = blockIdx.x;
    const uint64_t* src = interm + (size_t)b * EPVB;
    for (int k = 0; k < EPVB / 256; ++k) {
        uint64_t w = src[t + 256 * k];
        win2[(uint32_t)(w >> 32)] = (uint32_t)w;
    }
    __syncthreads();
    uint32_t* dst = dest + ((size_t)(half * VB_HALF + b)) * EPVB;
    for (int j = t; j < EPVB; j += 256) dst[j] = win2[j];
}

// ---------- per-iteration check-node kernel ----------
// Reconstructs incoming v2c_t-1 = aPrev*(post[v] - c2v_prev) bit-exactly from
// its own previous edgeinfo word (sequential) + post gather (8 MB footprint).
__global__ __launch_bounds__(256) void check_kernel(const float* __restrict__ prev_post,
                                                    const uint32_t* __restrict__ chk_edges,
                                                    const uint32_t* __restrict__ einfo_prev,
                                                    uint32_t* __restrict__ einfo_out,
                                                    const float* __restrict__ beta,
                                                    const float* __restrict__ alpha,
                                                    const float* __restrict__ thresholds,
                                                    int t) {
    __shared__ float tp[8];            // thresholds row t-1 (for c2v reconstruction)
    const int tid = threadIdx.x;
    const int tprev = (t > 0) ? (t - 1) : 0;
    if (tid < 8) tp[tid] = thresholds[tprev * 8 + tid];
    __syncthreads();

    const int c = blockIdx.x * 256 + tid;
    const float aPrev = (t > 0) ? alpha[t - 1] : 1.0f;
    const float b = beta[t];
    const float* thc = thresholds + t * 8;
    const float th1 = thc[1], th2 = thc[2], th3 = thc[3], th4 = thc[4];
    const float th5 = thc[5], th6 = thc[6], th7 = thc[7];

    const uint32_t wprev = einfo_prev[c];
    float mags[6];
    uint32_t sgn[6];
    uint32_t parity = 0;
    uint64_t minkey = ~0ull;
#pragma unroll
    for (int j = 0; j < 6; ++j) {
        uint32_t e = chk_edges[(size_t)c * 6 + j];
        uint32_t v = e / 3u;
        float p = prev_post[v];                         // the random gather (8 MB)
        uint32_t nib = (wprev >> (4 * j)) & 15u;
        float mg0 = tp[nib & 7u];
        float c2v = (nib & 8u) ? -mg0 : mg0;
        float x = aPrev * (p - c2v);                    // exact v2c reconstruction
        uint32_t s = (x < 0.0f) ? 1u : 0u;
        parity ^= s;
        sgn[j] = s;
        float mg = fabsf(x);
        mags[j] = mg;
        uint64_t key = (((uint64_t)__float_as_uint(mg)) << 3) | (uint32_t)j;
        minkey = (key < minkey) ? key : minkey;
    }
    float min1 = __uint_as_float((uint32_t)(minkey >> 3));
    uint32_t fs = (uint32_t)(minkey & 7u);
    float min2 = INFINITY;
#pragma unroll
    for (int j = 0; j < 6; ++j) {
        if ((uint32_t)j != fs) min2 = fminf(min2, mags[j]);
    }
    float m1 = fabsf(b * min1);
    float m2 = fabsf(b * min2);
    uint32_t q1 = (uint32_t)(m1 >= th1) + (uint32_t)(m1 >= th2) + (uint32_t)(m1 >= th3)
                + (uint32_t)(m1 >= th4) + (uint32_t)(m1 >= th5) + (uint32_t)(m1 >= th6)
                + (uint32_t)(m1 >= th7);
    uint32_t q2 = (uint32_t)(m2 >= th1) + (uint32_t)(m2 >= th2) + (uint32_t)(m2 >= th3)
                + (uint32_t)(m2 >= th4) + (uint32_t)(m2 >= th5) + (uint32_t)(m2 >= th6)
                + (uint32_t)(m2 >= th7);
    uint32_t signb = (b < 0.0f) ? 1u : 0u;
    uint32_t w = 0;
#pragma unroll
    for (int j = 0; j < 6; ++j) {
        uint32_t neg = signb ^ parity ^ sgn[j];
        uint32_t q = ((uint32_t)j == fs) ? q2 : q1;
        w |= ((neg << 3) | q) << (4 * j);
    }
    einfo_out[c] = w;
}

// ---------- per-iteration variable-node kernel ----------
__global__ __launch_bounds__(256) void var_kernel(const float* __restrict__ llr,
                                                  const uint32_t* __restrict__ dest,
                                                  const uint32_t* __restrict__ einfo,
                                                  const float* __restrict__ thresholds,
                                                  int t,
                                                  float* __restrict__ post_out,
                                                  int last,
                                                  float* __restrict__ out) {
    __shared__ float tl[8];
    if (threadIdx.x < 8) tl[threadIdx.x] = thresholds[t * 8 + threadIdx.x];
    __syncthreads();
    const int v = blockIdx.x * 256 + threadIdx.x;
    float c2[3];
#pragma unroll
    for (int i = 0; i < 3; ++i) {
        uint32_t d = dest[(size_t)3 * v + i];
        uint32_t w = einfo[d >> 3];                     // gather from 4 MB (L2-resident)
        uint32_t nib = (w >> (4 * (d & 7u))) & 15u;
        float mg = tl[nib & 7u];
        c2[i] = (nib & 8u) ? -mg : mg;
    }
    float s = (c2[0] + c2[1]) + c2[2];                  // reference summation order
    float post = llr[v] + s;
    post_out[v] = post;
    if (last) {
        out[v] = (post < 0.0f) ? 1.0f : 0.0f;           // decoded
        out[N_VAR + v] = post;                          // posterior
        if (v == 0) out[2 * N_VAR] = 10.0f;             // jnp.int32(T)
    }
}

extern "C" void kernel_launch(void* const* d_in, const int* in_sizes, int n_in,
                              void* d_out, int out_size, void* d_ws, size_t ws_size,
                              hipStream_t stream) {
    const float* llr        = (const float*)d_in[0];
    const int*   var_idx    = (const int*)d_in[1];   (void)var_idx;  // implicit e/3
    const int*   chk_idx    = (const int*)d_in[2];
    const float* beta       = (const float*)d_in[3];
    const float* alpha      = (const float*)d_in[4];
    const float* thresholds = (const float*)d_in[5];
    float* out = (float*)d_out;

    // workspace layout (75.5 MB total, matches proven-safe footprint):
    //   [0,   25.17M) chk_edges (E u32)
    //   [25.2,50.33M) dest      (E u32)
    //   [50.3,75.50M) interm    ((E/2) u64) — build scratch; after build:
    //                 post (N f32, 8.4M) + ebuf0 (M u32, 4.2M) + ebuf1 (M u32)
    //   [75.50M, +5K) cursors gcurA[512], gcurB[768]
    char* wsb = (char*)d_ws;
    uint32_t* chk_edges = (uint32_t*)wsb;
    uint32_t* dest      = (uint32_t*)(wsb + (size_t)E_EDGE * 4);
    char*     intermB   = wsb + (size_t)2 * E_EDGE * 4;
    uint64_t* interm    = (uint64_t*)intermB;
    float*    post      = (float*)intermB;
    uint32_t* ebuf0     = (uint32_t*)(intermB + (size_t)N_VAR * 4);
    uint32_t* ebuf1     = (uint32_t*)(intermB + (size_t)N_VAR * 4 + (size_t)M_CHK * 4);
    uint32_t* gcurA     = (uint32_t*)(wsb + (size_t)3 * E_EDGE * 4);
    uint32_t* gcurB     = gcurA + 512;

    hipMemsetAsync(gcurA, 0, (512 + 768) * 4, stream);

    const int B = 256;
    for (int h = 0; h < 2; ++h) {
        bin1_kernel<<<NBLK, B, 0, stream>>>(chk_idx, gcurA, interm, h);
        place1_kernel<<<CB_HALF, B, 0, stream>>>(interm, chk_edges, h);
    }
    for (int h = 0; h < 2; ++h) {
        bin2_kernel<<<NBLK, B, 0, stream>>>(chk_edges, gcurB, interm, h);
        place2_kernel<<<VB_HALF, B, 0, stream>>>(interm, dest, h);
    }
    // zero edgeinfo for t=0 (q=0 -> c2v = +thr[0] = 0 -> v2c0 = llr exactly)
    hipMemsetAsync(ebuf0, 0, (size_t)M_CHK * 4, stream);

    for (int t = 0; t < T_IT; ++t) {
        const float* prev_post = (t == 0) ? llr : post;
        uint32_t* einfo_prev = (t & 1) ? ebuf1 : ebuf0;
        uint32_t* einfo_out  = (t & 1) ? ebuf0 : ebuf1;
        check_kernel<<<M_CHK / B, B, 0, stream>>>(prev_post, chk_edges, einfo_prev, einfo_out,
                                                  beta, alpha, thresholds, t);
        var_kernel<<<N_VAR / B, B, 0, stream>>>(llr, dest, einfo_out, thresholds, t, post,
                                                (t == T_IT - 1) ? 1 : 0, out);
    }
}